// Round 4
// baseline (176.168 us; speedup 1.0000x reference)
//
#include <hip/hip_runtime.h>
#include <stdint.h>

#define D_MODEL 1024
#define NH      16
#define DKH     64
#define SEQLEN  2048
#define BATCH   2
#define KDIM    1024   // inner dim of all projections

typedef __attribute__((ext_vector_type(8))) short          short8;   // 8 bf16 (4 VGPRs)
typedef __attribute__((ext_vector_type(4))) short          bf16x4;   // 4 bf16 (2 VGPRs)
typedef __attribute__((ext_vector_type(8))) unsigned short ushort8;
typedef __attribute__((ext_vector_type(4))) unsigned short usht4;    // 'ushort4' is taken by HIP
typedef __attribute__((ext_vector_type(4))) float          f32x4;

// exp2(q·k) where q pre-scaled by 0.125*log2(e) == exp(q·k/8)
#define QSCALE 0.18033688011112042f

// ---------- helpers ----------
__device__ __forceinline__ unsigned short f2bf(float f) {
    union { float f; unsigned u; } v; v.f = f;
    unsigned u = v.u;
    unsigned r = (u + 0x7FFFu + ((u >> 16) & 1u)) >> 16;   // RNE
    return (unsigned short)r;
}
__device__ __forceinline__ unsigned fbits(float f) {
    union { float f; unsigned u; } v; v.f = f; return v.u;
}

__device__ __forceinline__ void gload_lds16(const unsigned short* g, unsigned short* l) {
    __builtin_amdgcn_global_load_lds(
        (__attribute__((address_space(1))) void*)(g),
        (__attribute__((address_space(3))) void*)(l), 16, 0, 0);
}

// ---------- kernel 0: fp32 -> bf16 convert (5 tensors) + RoPE cos/sin table ----------
__global__ void cvt_all(const float* __restrict__ X,  const float* __restrict__ Wq,
                        const float* __restrict__ Wk, const float* __restrict__ Wv,
                        const float* __restrict__ Wo, const int* __restrict__ pos,
                        unsigned short* __restrict__ Xb,  unsigned short* __restrict__ Wqb,
                        unsigned short* __restrict__ Wkb, unsigned short* __restrict__ Wvb,
                        unsigned short* __restrict__ Wob, float2* __restrict__ tbl) {
    const int z = blockIdx.y;
    if (z == 5) {
        int i = blockIdx.x * 256 + threadIdx.x;   // tbl[s][j], 2048*32 entries
        if (i < 65536) {
            int s = i >> 5, j = i & 31;
            float freq = expf(-((float)(2 * j) * (1.0f / 64.0f)) * 9.210340371976184f);
            float ang = (float)pos[s] * freq;
            float sn, cn;
            sincosf(ang, &sn, &cn);
            tbl[i] = make_float2(cn, sn);
        }
        return;
    }
    const float* src; unsigned short* dst; int n;
    if (z == 0)      { src = X;  dst = Xb;  n = 4194304; }
    else if (z == 1) { src = Wq; dst = Wqb; n = 1048576; }
    else if (z == 2) { src = Wk; dst = Wkb; n = 1048576; }
    else if (z == 3) { src = Wv; dst = Wvb; n = 1048576; }
    else             { src = Wo; dst = Wob; n = 1048576; }
    int i = (blockIdx.x * 256 + threadIdx.x) * 8;
    if (i >= n) return;
    float4 a = *(const float4*)(src + i);
    float4 b = *(const float4*)(src + i + 4);
    ushort8 o;
    o[0] = f2bf(a.x); o[1] = f2bf(a.y); o[2] = f2bf(a.z); o[3] = f2bf(a.w);
    o[4] = f2bf(b.x); o[5] = f2bf(b.y); o[6] = f2bf(b.z); o[7] = f2bf(b.w);
    *(ushort8*)(dst + i) = o;
}

// ---------- shared GEMM core: C[128x128] = A[m0:,:] * W[n0:,:]^T, K=1024, BK=64 ----------
// 2-PHASE PIPELINED (T3-minimum): double-buffered LDS, ONE barrier per K-step.
// Each iteration issues global_load_lds for tile k+64 into the idle buffer BEFORE
// the ds_read+MFMA phase on the current buffer; the compiler-emitted
// s_waitcnt vmcnt(0) at the trailing __syncthreads then lands AFTER the whole MFMA
// phase has covered the load latency (vs the old stage->wait->compute serial loop).
// LDS rows are 128B so naive frag reads would be 16-way bank-conflicted; fixed by
// XOR-swizzling the GLOBAL source colgroup during staging (LDS dest is fixed
// lane-order) and applying the same xor on fragment reads: slot s of row r holds
// global k-group (s ^ (r&7)).
__device__ __forceinline__ void gemm_core_128(
    const unsigned short* __restrict__ A, const unsigned short* __restrict__ W,
    unsigned short* a_lds, unsigned short* b_lds,   // each 2 x 8192 ushorts (dbuf)
    int m0, int n0, f32x4 acc[4][4])
{
    const int tid  = threadIdx.x;
    const int lane = tid & 63;
    const int w    = tid >> 6;
    const int quad = lane >> 4;
    const int l16  = lane & 15;
    const int wm   = w & 1, wn = w >> 1;

    const int row_in = lane >> 3;                 // 0..7 row within 8-row chunk
    const int cg     = ((lane & 7) ^ row_in) * 8; // xor-swizzled k-group offset (elems)

    #pragma unroll
    for (int mi = 0; mi < 4; mi++)
        #pragma unroll
        for (int ni = 0; ni < 4; ni++) {
            f32x4 z = {0.f, 0.f, 0.f, 0.f};
            acc[mi][ni] = z;
        }

    const int x7 = l16 & 7;                       // = row&7 for all frag rows

    // prologue: stage k=0 into buffer 0
    #pragma unroll
    for (int j = 0; j < 4; ++j) {
        int c = w * 4 + j;                        // chunk: 8 rows x 64 k (1KB)
        gload_lds16(A + (size_t)(m0 + c * 8 + row_in) * KDIM + cg, &a_lds[c * 512]);
        gload_lds16(W + (size_t)(n0 + c * 8 + row_in) * KDIM + cg, &b_lds[c * 512]);
    }
    __syncthreads();                              // vmcnt(0) drain -> buf0 ready

    int cur = 0;
    for (int kk = 0; kk < KDIM; kk += 64) {
        // stage NEXT tile into the idle buffer; overlaps with MFMA below
        if (kk + 64 < KDIM) {
            const int nxt = cur ^ 1;
            #pragma unroll
            for (int j = 0; j < 4; ++j) {
                int c = w * 4 + j;
                gload_lds16(A + (size_t)(m0 + c * 8 + row_in) * KDIM + kk + 64 + cg,
                            &a_lds[nxt * 8192 + c * 512]);
                gload_lds16(W + (size_t)(n0 + c * 8 + row_in) * KDIM + kk + 64 + cg,
                            &b_lds[nxt * 8192 + c * 512]);
            }
        }

        const unsigned short* al = &a_lds[cur * 8192];
        const unsigned short* bl = &b_lds[cur * 8192];
        short8 af[2][4], bf[2][4];
        #pragma unroll
        for (int kk2 = 0; kk2 < 2; kk2++)
            #pragma unroll
            for (int i = 0; i < 4; i++) {
                int g = (kk2 * 4 + quad) ^ x7;    // de-swizzle
                af[kk2][i] = *(const short8*)&al[(wm * 64 + i * 16 + l16) * 64 + g * 8];
                bf[kk2][i] = *(const short8*)&bl[(wn * 64 + i * 16 + l16) * 64 + g * 8];
            }
        #pragma unroll
        for (int kk2 = 0; kk2 < 2; kk2++)
            #pragma unroll
            for (int mi = 0; mi < 4; mi++)
                #pragma unroll
                for (int ni = 0; ni < 4; ni++)
                    acc[mi][ni] = __builtin_amdgcn_mfma_f32_16x16x32_bf16(af[kk2][mi], bf[kk2][ni], acc[mi][ni], 0, 0, 0);

        // one barrier per K-step: (a) vmcnt(0) -> next buffer landed,
        // (b) all waves done reading buf[cur] before it's restaged next iter
        __syncthreads();
        cur ^= 1;
    }
}

// ---------- kernel 1: QKV projection + fused RoPE (Q,K) + V^T transpose-store ----------
__global__ __launch_bounds__(256, 2)
void gemm_qkv(const unsigned short* __restrict__ X,
              const unsigned short* __restrict__ Wq,
              const unsigned short* __restrict__ Wk,
              const unsigned short* __restrict__ Wv,
              const float2* __restrict__ tbl,
              unsigned short* __restrict__ q_ws,
              unsigned short* __restrict__ k_ws,
              unsigned short* __restrict__ v_ws)
{
    __shared__ __align__(16) unsigned short a_lds[2 * 128 * 64];   // dbuf
    __shared__ __align__(16) unsigned short b_lds[2 * 128 * 64];   // dbuf
    __shared__ __align__(16) unsigned short t_lds[32 * 136];       // V transpose staging

    const int z = blockIdx.z;
    const unsigned short* W = (z == 0) ? Wq : ((z == 1) ? Wk : Wv);
    const int m0 = blockIdx.x * 128, n0 = blockIdx.y * 128;

    f32x4 acc[4][4];
    gemm_core_128(X, W, a_lds, b_lds, m0, n0, acc);

    const int tid  = threadIdx.x;
    const int lane = tid & 63;
    const int w    = tid >> 6;
    const int quad = lane >> 4;
    const int l16  = lane & 15;
    const int wm   = w & 1, wn = w >> 1;

    if (z == 2) {
        // ---- V: transpose 128x128 tile through LDS, store [bh][d][s] coalesced ----
        const int bx = m0 >> 11;                 // batch
        const int c_local_w = wn * 16 + l16;     // writer column slot 0..31
        const int rd_c = tid >> 3;               // reader column slot 0..31
        const int rd_s = (tid & 7) * 16;         // reader s-offset
        #pragma unroll
        for (int ni = 0; ni < 4; ni++) {
            __syncthreads();                     // prior pass reads done
            #pragma unroll
            for (int mi = 0; mi < 4; mi++) {
                usht4 v4;
                #pragma unroll
                for (int r = 0; r < 4; r++) v4[r] = f2bf(acc[mi][ni][r]);
                *(usht4*)&t_lds[c_local_w * 136 + wm * 64 + mi * 16 + quad * 4] = v4;
            }
            __syncthreads();
            int col = n0 + (rd_c >> 4) * 64 + ni * 16 + (rd_c & 15);
            int h = col >> 6, d = col & 63;
            size_t base = (size_t)(bx * NH + h) * DKH * SEQLEN + (size_t)d * SEQLEN
                        + (m0 & 2047) + rd_s;
            ushort8 x0 = *(ushort8*)&t_lds[rd_c * 136 + rd_s];
            ushort8 x1 = *(ushort8*)&t_lds[rd_c * 136 + rd_s + 8];
            *(ushort8*)&v_ws[base]     = x0;
            *(ushort8*)&v_ws[base + 8] = x1;
        }
    } else {
        // ---- Q/K: fused RoPE on fp32 acc, then round once ----
        unsigned short* dst = (z == 0) ? q_ws : k_ws;
        const float sc = (z == 0) ? QSCALE : 1.0f;
        #pragma unroll
        for (int mi = 0; mi < 4; mi++)
            #pragma unroll
            for (int ni = 0; ni < 4; ni++)
                #pragma unroll
                for (int r = 0; r < 4; r++) {
                    int row = m0 + wm * 64 + mi * 16 + quad * 4 + r;
                    int col = n0 + wn * 64 + ni * 16 + l16;
                    int b = row >> 11, s = row & 2047;
                    int h = col >> 6,  d = col & 63;
                    float val = acc[mi][ni][r];
                    float other = __shfl_xor(val, 1);     // RoPE partner: col^1 == lane^1
                    float2 cs = tbl[s * 32 + (d >> 1)];
                    float rv = (d & 1) ? (other * cs.y + val * cs.x)
                                       : (val * cs.x - other * cs.y);
                    dst[(size_t)(b * NH + h) * SEQLEN * DKH + (size_t)s * DKH + d] =
                        f2bf(rv * sc);
                }
    }
}

// ---------- kernel 2: causal flash attention (S^T trick; 128q x 128k blocks) ----------
// grid (bh=32, y=16): one q-supertile per block. qt = (y<8) ? y : 23-y, so blocks
// ID c and c+256 (same CU under round-robin dispatch) carry qt pairs (a, 15-a):
// every CU gets 17 key-tile iterations total with TWO resident blocks.
// launch_bounds (512, 2): (512,4) forced 64-VGPR cap -> scratch spills (+20us).
// ID%8 = bh%8 -> all blocks of one bh on one XCD (K/V L2 locality).
// waves 0-3 take keys [s0,s0+64), waves 4-7 keys [s0+64,s0+128); group-1 partials
// combined into group 0 through an LDS buffer aliased over k_lds/v_lds at the end.
// S^T = K·Q^T: C-layout lane holds P[q=l16][key=quad*4+r] == B-operand layout of
// mfma_16x16x16 -> PV without cross-lane transform. O^T in C-layout.
__global__ __launch_bounds__(512, 2)
void attn_kernel(const unsigned short* __restrict__ q_ws,
                 const unsigned short* __restrict__ k_ws,
                 const unsigned short* __restrict__ v_ws,
                 unsigned short* __restrict__ ao)
{
    // k_lds 128*72 ushorts (18432B) + v_lds 64*136 ushorts (17408B) = 35840B.
    // Reduction view (aliased): redO 8192 f32 (32KB) + redL 512 f32 (2KB) = 34816B.
    __shared__ __align__(16) unsigned short smem[17920];
    unsigned short* k_lds = smem;                 // [key][d] pad->72
    unsigned short* v_lds = smem + 128 * 72;      // [d][key] pad->136
    float* redO = (float*)smem;
    float* redL = redO + 8192;

    const int bh  = blockIdx.x;
    const int y   = blockIdx.y;         // 0..15
    const int qt2 = (y < 8) ? y : (23 - y);   // CU-pairing balance map
    const int tid = threadIdx.x, lane = tid & 63, w = tid >> 6;
    const int quad = lane >> 4, l16 = lane & 15;
    const int g   = w >> 2;             // key-half group (0: keys 0-63, 1: keys 64-127)
    const int w4  = w & 3;              // query strip owner within group
    const int nf0 = g * 4;

    const size_t kqbase = (size_t)bh * SEQLEN * DKH;
    const size_t vbase  = (size_t)bh * DKH * SEQLEN;
    const int b = bh >> 4, h = bh & 15;

    // staging (512 threads, 2 chunks each)
    const int krow = tid >> 3, kcol = (tid & 7) * 8;     // K: rows krow, krow+64
    const int vrow = tid >> 4, vcol = (tid & 15) * 8;    // V: rows vrow, vrow+32

    const int q0  = qt2 * 128;
    const int nt  = qt2 + 1;              // # of 128-key tiles
    const int qwbase = q0 + w4 * 32;      // this wave's 32 queries

    short8 aq[2][2];
    #pragma unroll
    for (int st = 0; st < 2; st++)
        #pragma unroll
        for (int kc = 0; kc < 2; kc++)
            aq[st][kc] = *(const short8*)(q_ws + kqbase +
                (size_t)(qwbase + st * 16 + l16) * DKH + kc * 32 + quad * 8);

    f32x4 o_acc[2][4];
    #pragma unroll
    for (int st = 0; st < 2; st++)
        #pragma unroll
        for (int df = 0; df < 4; df++) { f32x4 z = {0.f,0.f,0.f,0.f}; o_acc[st][df] = z; }
    float lsum[2] = {0.f, 0.f};

    // prefetch tile 0
    ushort8 kreg[2], vreg[2];
    #pragma unroll
    for (int rr = 0; rr < 2; ++rr) {
        kreg[rr] = *(const ushort8*)(k_ws + kqbase + (size_t)(krow + rr * 64) * DKH + kcol);
        vreg[rr] = *(const ushort8*)(v_ws + vbase + (size_t)(vrow + rr * 32) * SEQLEN + vcol);
    }

    for (int t = 0; t < nt; ++t) {
        const int s0 = t * 128;
        __syncthreads();
        #pragma unroll
        for (int rr = 0; rr < 2; ++rr) {
            *(ushort8*)&k_lds[(krow + rr * 64) * 72 + kcol]  = kreg[rr];
            *(ushort8*)&v_lds[(vrow + rr * 32) * 136 + vcol] = vreg[rr];
        }
        __syncthreads();
        if (t < nt - 1) {
            int s1 = s0 + 128;
            #pragma unroll
            for (int rr = 0; rr < 2; ++rr) {
                kreg[rr] = *(const ushort8*)(k_ws + kqbase + (size_t)(s1 + krow + rr * 64) * DKH + kcol);
                vreg[rr] = *(const ushort8*)(v_ws + vbase + (size_t)(vrow + rr * 32) * SEQLEN + s1 + vcol);
            }
        }

        const bool diag = (t == nt - 1);
        #pragma unroll
        for (int nfi = 0; nfi < 4; nfi++) {
            const int nf = nf0 + nfi;
            short8 kf0 = *(const short8*)&k_lds[(nf * 16 + l16) * 72 + 0 * 32 + quad * 8];
            short8 kf1 = *(const short8*)&k_lds[(nf * 16 + l16) * 72 + 1 * 32 + quad * 8];
            bf16x4 vf[4];
            #pragma unroll
            for (int df = 0; df < 4; df++)
                vf[df] = *(const bf16x4*)&v_lds[(df * 16 + l16) * 136 + nf * 16 + quad * 4];

            #pragma unroll
            for (int st = 0; st < 2; st++) {
                f32x4 s = {0.f,0.f,0.f,0.f};
                s = __builtin_amdgcn_mfma_f32_16x16x32_bf16(kf0, aq[st][0], s, 0, 0, 0);
                s = __builtin_amdgcn_mfma_f32_16x16x32_bf16(kf1, aq[st][1], s, 0, 0, 0);

                if (diag) {
                    int qg = qwbase + st * 16 + l16;
                    int kg = s0 + nf * 16 + quad * 4;
                    #pragma unroll
                    for (int r = 0; r < 4; r++)
                        s[r] = (kg + r <= qg) ? __builtin_amdgcn_exp2f(s[r]) : 0.f;
                } else {
                    #pragma unroll
                    for (int r = 0; r < 4; r++)
                        s[r] = __builtin_amdgcn_exp2f(s[r]);
                }
                lsum[st] += s[0] + s[1] + s[2] + s[3];

                union { unsigned u[2]; bf16x4 v; } pk;
                pk.u[0] = __builtin_amdgcn_perm(fbits(s[1]), fbits(s[0]), 0x07060302u);
                pk.u[1] = __builtin_amdgcn_perm(fbits(s[3]), fbits(s[2]), 0x07060302u);

                #pragma unroll
                for (int df = 0; df < 4; df++)
                    o_acc[st][df] = __builtin_amdgcn_mfma_f32_16x16x16bf16_1k(vf[df], pk.v, o_acc[st][df], 0, 0, 0);
            }
        }
    }

    // ---- combine group 1 partials into group 0 through LDS, then epilogue ----
    __syncthreads();                       // all waves done reading k_lds/v_lds
    if (g == 1) {
        #pragma unroll
        for (int st = 0; st < 2; st++) {
            #pragma unroll
            for (int df = 0; df < 4; df++)
                *(f32x4*)&redO[(((w4 * 2 + st) * 4 + df) << 8) + lane * 4] = o_acc[st][df];
            redL[(w4 * 2 + st) * 64 + lane] = lsum[st];
        }
    }
    __syncthreads();
    if (g == 0) {
        #pragma unroll
        for (int st = 0; st < 2; st++) {
            #pragma unroll
            for (int df = 0; df < 4; df++) {
                f32x4 o1 = *(const f32x4*)&redO[(((w4 * 2 + st) * 4 + df) << 8) + lane * 4];
                o_acc[st][df] += o1;
            }
            float rs = lsum[st] + redL[(w4 * 2 + st) * 64 + lane];
            rs += __shfl_xor(rs, 16);
            rs += __shfl_xor(rs, 32);
            float inv = 1.0f / rs;
            int qg = qwbase + st * 16 + l16;
            #pragma unroll
            for (int df = 0; df < 4; df++) {
                usht4 ov;
                #pragma unroll
                for (int r = 0; r < 4; r++) ov[r] = f2bf(o_acc[st][df][r] * inv);
                *(usht4*)&ao[(size_t)(b * SEQLEN + qg) * D_MODEL + h * DKH + df * 16 + quad * 4] = ov;
            }
        }
    }
}

// ---------- kernel 3: output projection (fp32 output) ----------
__global__ __launch_bounds__(256, 2)
void gemm_out(const unsigned short* __restrict__ AO,
              const unsigned short* __restrict__ Wo,
              float* __restrict__ out)
{
    __shared__ __align__(16) unsigned short a_lds[2 * 128 * 64];   // dbuf
    __shared__ __align__(16) unsigned short b_lds[2 * 128 * 64];   // dbuf

    const int m0 = blockIdx.x * 128, n0 = blockIdx.y * 128;
    f32x4 acc[4][4];
    gemm_core_128(AO, Wo, a_lds, b_lds, m0, n0, acc);

    const int lane = threadIdx.x & 63;
    const int w    = threadIdx.x >> 6;
    const int quad = lane >> 4;
    const int l16  = lane & 15;
    const int wm   = w & 1, wn = w >> 1;

    #pragma unroll
    for (int mi = 0; mi < 4; mi++)
        #pragma unroll
        for (int ni = 0; ni < 4; ni++)
            #pragma unroll
            for (int r = 0; r < 4; r++) {
                int row = m0 + wm * 64 + mi * 16 + quad * 4 + r;
                int col = n0 + wn * 64 + ni * 16 + l16;
                out[(size_t)row * D_MODEL + col] = acc[mi][ni][r];
            }
}

// ---------- launch ----------
extern "C" void kernel_launch(void* const* d_in, const int* in_sizes, int n_in,
                              void* d_out, int out_size, void* d_ws, size_t ws_size,
                              hipStream_t stream) {
    const float* X  = (const float*)d_in[0];
    const int*   pos = (const int*)d_in[1];
    const float* Wq = (const float*)d_in[2];
    const float* Wk = (const float*)d_in[3];
    const float* Wv = (const float*)d_in[4];
    const float* Wo = (const float*)d_in[5];
    float* out = (float*)d_out;

    // ws (ushorts): Xb 4M | Wqb 1M | Wkb 1M | Wvb 1M | Wob 1M | q 4M | k 4M | v^T 4M | ao 4M | tbl 512KB
    unsigned short* Xb  = (unsigned short*)d_ws;
    unsigned short* Wqb = Xb + 4194304;
    unsigned short* Wkb = Wqb + 1048576;
    unsigned short* Wvb = Wkb + 1048576;
    unsigned short* Wob = Wvb + 1048576;
    unsigned short* q_ws = Wob + 1048576;
    unsigned short* k_ws = q_ws + 4194304;
    unsigned short* v_ws = k_ws + 4194304;
    unsigned short* ao   = v_ws + 4194304;
    float2* tbl = (float2*)(ao + 4194304);

    cvt_all<<<dim3(2048, 6), dim3(256), 0, stream>>>(X, Wq, Wk, Wv, Wo, pos,
                                                     Xb, Wqb, Wkb, Wvb, Wob, tbl);
    gemm_qkv<<<dim3(32, 8, 3), dim3(256), 0, stream>>>(Xb, Wqb, Wkb, Wvb, tbl, q_ws, k_ws, v_ws);
    attn_kernel<<<dim3(32, 16), dim3(512), 0, stream>>>(q_ws, k_ws, v_ws, ao);
    gemm_out<<<dim3(32, 8), dim3(256), 0, stream>>>(ao, Wob, out);
}

// Round 5
// 163.130 us; speedup vs baseline: 1.0799x; 1.0799x over previous
//
#include <hip/hip_runtime.h>
#include <stdint.h>

#define D_MODEL 1024
#define NH      16
#define DKH     64
#define SEQLEN  2048
#define BATCH   2
#define KDIM    1024   // inner dim of all projections

typedef __attribute__((ext_vector_type(8))) short          short8;   // 8 bf16 (4 VGPRs)
typedef __attribute__((ext_vector_type(4))) short          bf16x4;   // 4 bf16 (2 VGPRs)
typedef __attribute__((ext_vector_type(8))) unsigned short ushort8;
typedef __attribute__((ext_vector_type(4))) unsigned short usht4;    // 'ushort4' is taken by HIP
typedef __attribute__((ext_vector_type(4))) float          f32x4;

// exp2(q·k) where q pre-scaled by 0.125*log2(e) == exp(q·k/8)
#define QSCALE 0.18033688011112042f

// ---------- helpers ----------
__device__ __forceinline__ unsigned short f2bf(float f) {
    union { float f; unsigned u; } v; v.f = f;
    unsigned u = v.u;
    unsigned r = (u + 0x7FFFu + ((u >> 16) & 1u)) >> 16;   // RNE
    return (unsigned short)r;
}
__device__ __forceinline__ unsigned fbits(float f) {
    union { float f; unsigned u; } v; v.f = f; return v.u;
}

__device__ __forceinline__ void gload_lds16(const unsigned short* g, unsigned short* l) {
    __builtin_amdgcn_global_load_lds(
        (__attribute__((address_space(1))) void*)(g),
        (__attribute__((address_space(3))) void*)(l), 16, 0, 0);
}

// ---------- kernel 0: fp32 -> bf16 convert (5 tensors) + RoPE cos/sin table ----------
__global__ void cvt_all(const float* __restrict__ X,  const float* __restrict__ Wq,
                        const float* __restrict__ Wk, const float* __restrict__ Wv,
                        const float* __restrict__ Wo, const int* __restrict__ pos,
                        unsigned short* __restrict__ Xb,  unsigned short* __restrict__ Wqb,
                        unsigned short* __restrict__ Wkb, unsigned short* __restrict__ Wvb,
                        unsigned short* __restrict__ Wob, float2* __restrict__ tbl) {
    const int z = blockIdx.y;
    if (z == 5) {
        int i = blockIdx.x * 256 + threadIdx.x;   // tbl[s][j], 2048*32 entries
        if (i < 65536) {
            int s = i >> 5, j = i & 31;
            float freq = expf(-((float)(2 * j) * (1.0f / 64.0f)) * 9.210340371976184f);
            float ang = (float)pos[s] * freq;
            float sn, cn;
            sincosf(ang, &sn, &cn);
            tbl[i] = make_float2(cn, sn);
        }
        return;
    }
    const float* src; unsigned short* dst; int n;
    if (z == 0)      { src = X;  dst = Xb;  n = 4194304; }
    else if (z == 1) { src = Wq; dst = Wqb; n = 1048576; }
    else if (z == 2) { src = Wk; dst = Wkb; n = 1048576; }
    else if (z == 3) { src = Wv; dst = Wvb; n = 1048576; }
    else             { src = Wo; dst = Wob; n = 1048576; }
    int i = (blockIdx.x * 256 + threadIdx.x) * 8;
    if (i >= n) return;
    float4 a = *(const float4*)(src + i);
    float4 b = *(const float4*)(src + i + 4);
    ushort8 o;
    o[0] = f2bf(a.x); o[1] = f2bf(a.y); o[2] = f2bf(a.z); o[3] = f2bf(a.w);
    o[4] = f2bf(b.x); o[5] = f2bf(b.y); o[6] = f2bf(b.z); o[7] = f2bf(b.w);
    *(ushort8*)(dst + i) = o;
}

// ---------- GEMM core A (qkv): C[128x128] = A[m0:,:] * W[n0:,:]^T, K=1024, BK=64 ----------
// SINGLE-BUFFER, 2 barriers per K-step. Proven ~600 TF shape at 3 blocks/CU.
// (Round-4 lesson: double-buffering this core pushed LDS 41.5->74 KB, dropping
// 3->2 resident blocks against a 3-blocks/CU grid -> net regression. Occupancy IS
// the latency-hiding mechanism here; keep LDS small.)
// LDS rows are 128B so naive frag reads would be 16-way bank-conflicted; fixed by
// XOR-swizzling the GLOBAL source colgroup during global_load_lds staging (LDS dest
// is fixed lane-order) and applying the same xor on fragment reads: slot s of row r
// holds global k-group (s ^ (r&7)).
__device__ __forceinline__ void gemm_core_128(
    const unsigned short* __restrict__ A, const unsigned short* __restrict__ W,
    unsigned short* a_lds, unsigned short* b_lds,
    int m0, int n0, f32x4 acc[4][4])
{
    const int tid  = threadIdx.x;
    const int lane = tid & 63;
    const int w    = tid >> 6;
    const int quad = lane >> 4;
    const int l16  = lane & 15;
    const int wm   = w & 1, wn = w >> 1;

    const int row_in = lane >> 3;                 // 0..7 row within 8-row chunk
    const int cg     = ((lane & 7) ^ row_in) * 8; // xor-swizzled k-group offset (elems)

    #pragma unroll
    for (int mi = 0; mi < 4; mi++)
        #pragma unroll
        for (int ni = 0; ni < 4; ni++) {
            f32x4 z = {0.f, 0.f, 0.f, 0.f};
            acc[mi][ni] = z;
        }

    const int x7 = l16 & 7;                       // = row&7 for all frag rows

    for (int kk = 0; kk < KDIM; kk += 64) {
        __syncthreads();
        #pragma unroll
        for (int j = 0; j < 4; ++j) {
            int c = w * 4 + j;                    // chunk: 8 rows x 64 k (1KB)
            gload_lds16(A + (size_t)(m0 + c * 8 + row_in) * KDIM + kk + cg, &a_lds[c * 512]);
            gload_lds16(W + (size_t)(n0 + c * 8 + row_in) * KDIM + kk + cg, &b_lds[c * 512]);
        }
        __syncthreads();

        short8 af[2][4], bf[2][4];
        #pragma unroll
        for (int kk2 = 0; kk2 < 2; kk2++)
            #pragma unroll
            for (int i = 0; i < 4; i++) {
                int g = (kk2 * 4 + quad) ^ x7;    // de-swizzle
                af[kk2][i] = *(const short8*)&a_lds[(wm * 64 + i * 16 + l16) * 64 + g * 8];
                bf[kk2][i] = *(const short8*)&b_lds[(wn * 64 + i * 16 + l16) * 64 + g * 8];
            }
        #pragma unroll
        for (int kk2 = 0; kk2 < 2; kk2++)
            #pragma unroll
            for (int mi = 0; mi < 4; mi++)
                #pragma unroll
                for (int ni = 0; ni < 4; ni++)
                    acc[mi][ni] = __builtin_amdgcn_mfma_f32_16x16x32_bf16(af[kk2][mi], bf[kk2][ni], acc[mi][ni], 0, 0, 0);
    }
}

// ---------- GEMM core B (out): C[128x64] = A * W^T, DOUBLE-BUFFERED, 1 barrier/step ----
// gemm_out's grid gives 2 blocks/CU (512 blocks); LDS 48KB keeps both resident.
// Pipelining belongs HERE (nothing to lose: old shape was 1 block/CU, zero overlap).
// Each iteration issues global_load_lds for tile k+64 into the idle buffer BEFORE
// the ds_read+MFMA phase; the compiler's vmcnt(0) drain at the single trailing
// __syncthreads lands after MFMA has covered the load latency.
__device__ __forceinline__ void gemm_core_128x64_db(
    const unsigned short* __restrict__ A, const unsigned short* __restrict__ W,
    unsigned short* a_lds, unsigned short* b_lds,   // a: 2*8192, b: 2*4096 ushorts
    int m0, int n0, f32x4 acc[4][2])
{
    const int tid  = threadIdx.x;
    const int lane = tid & 63;
    const int w    = tid >> 6;
    const int quad = lane >> 4;
    const int l16  = lane & 15;
    const int wm   = w & 1, wn = w >> 1;          // 2(m) x 2(n) waves, 64x32 each

    const int row_in = lane >> 3;
    const int cg     = ((lane & 7) ^ row_in) * 8;

    #pragma unroll
    for (int mi = 0; mi < 4; mi++)
        #pragma unroll
        for (int ni = 0; ni < 2; ni++) {
            f32x4 z = {0.f, 0.f, 0.f, 0.f};
            acc[mi][ni] = z;
        }

    const int x7 = l16 & 7;

    // prologue: stage k=0 into buffer 0
    #pragma unroll
    for (int j = 0; j < 4; ++j) {
        int c = w * 4 + j;                        // A: 16 chunks of 8 rows
        gload_lds16(A + (size_t)(m0 + c * 8 + row_in) * KDIM + cg, &a_lds[c * 512]);
    }
    #pragma unroll
    for (int j = 0; j < 2; ++j) {
        int c = w * 2 + j;                        // B: 8 chunks of 8 rows
        gload_lds16(W + (size_t)(n0 + c * 8 + row_in) * KDIM + cg, &b_lds[c * 512]);
    }
    __syncthreads();

    int cur = 0;
    for (int kk = 0; kk < KDIM; kk += 64) {
        if (kk + 64 < KDIM) {
            const int nxt = cur ^ 1;
            #pragma unroll
            for (int j = 0; j < 4; ++j) {
                int c = w * 4 + j;
                gload_lds16(A + (size_t)(m0 + c * 8 + row_in) * KDIM + kk + 64 + cg,
                            &a_lds[nxt * 8192 + c * 512]);
            }
            #pragma unroll
            for (int j = 0; j < 2; ++j) {
                int c = w * 2 + j;
                gload_lds16(W + (size_t)(n0 + c * 8 + row_in) * KDIM + kk + 64 + cg,
                            &b_lds[nxt * 4096 + c * 512]);
            }
        }

        const unsigned short* al = &a_lds[cur * 8192];
        const unsigned short* bl = &b_lds[cur * 4096];
        short8 af[2][4], bf[2][2];
        #pragma unroll
        for (int kk2 = 0; kk2 < 2; kk2++) {
            #pragma unroll
            for (int i = 0; i < 4; i++) {
                int g = (kk2 * 4 + quad) ^ x7;
                af[kk2][i] = *(const short8*)&al[(wm * 64 + i * 16 + l16) * 64 + g * 8];
            }
            #pragma unroll
            for (int i = 0; i < 2; i++) {
                int g = (kk2 * 4 + quad) ^ x7;
                bf[kk2][i] = *(const short8*)&bl[(wn * 32 + i * 16 + l16) * 64 + g * 8];
            }
        }
        #pragma unroll
        for (int kk2 = 0; kk2 < 2; kk2++)
            #pragma unroll
            for (int mi = 0; mi < 4; mi++)
                #pragma unroll
                for (int ni = 0; ni < 2; ni++)
                    acc[mi][ni] = __builtin_amdgcn_mfma_f32_16x16x32_bf16(af[kk2][mi], bf[kk2][ni], acc[mi][ni], 0, 0, 0);

        __syncthreads();       // vmcnt(0): next buffer landed; cur readers done
        cur ^= 1;
    }
}

// ---------- kernel 1: QKV projection + fused RoPE (Q,K) + V^T transpose-store ----------
__global__ __launch_bounds__(256, 2)
void gemm_qkv(const unsigned short* __restrict__ X,
              const unsigned short* __restrict__ Wq,
              const unsigned short* __restrict__ Wk,
              const unsigned short* __restrict__ Wv,
              const float2* __restrict__ tbl,
              unsigned short* __restrict__ q_ws,
              unsigned short* __restrict__ k_ws,
              unsigned short* __restrict__ v_ws)
{
    __shared__ __align__(16) unsigned short a_lds[128 * 64];
    __shared__ __align__(16) unsigned short b_lds[128 * 64];
    __shared__ __align__(16) unsigned short t_lds[32 * 136];   // V transpose staging

    const int z = blockIdx.z;
    const unsigned short* W = (z == 0) ? Wq : ((z == 1) ? Wk : Wv);
    const int m0 = blockIdx.x * 128, n0 = blockIdx.y * 128;

    f32x4 acc[4][4];
    gemm_core_128(X, W, a_lds, b_lds, m0, n0, acc);

    const int tid  = threadIdx.x;
    const int lane = tid & 63;
    const int w    = tid >> 6;
    const int quad = lane >> 4;
    const int l16  = lane & 15;
    const int wm   = w & 1, wn = w >> 1;

    if (z == 2) {
        // ---- V: transpose 128x128 tile through LDS, store [bh][d][s] coalesced ----
        const int bx = m0 >> 11;                 // batch
        const int c_local_w = wn * 16 + l16;     // writer column slot 0..31
        const int rd_c = tid >> 3;               // reader column slot 0..31
        const int rd_s = (tid & 7) * 16;         // reader s-offset
        #pragma unroll
        for (int ni = 0; ni < 4; ni++) {
            __syncthreads();                     // prior pass reads done
            #pragma unroll
            for (int mi = 0; mi < 4; mi++) {
                usht4 v4;
                #pragma unroll
                for (int r = 0; r < 4; r++) v4[r] = f2bf(acc[mi][ni][r]);
                *(usht4*)&t_lds[c_local_w * 136 + wm * 64 + mi * 16 + quad * 4] = v4;
            }
            __syncthreads();
            int col = n0 + (rd_c >> 4) * 64 + ni * 16 + (rd_c & 15);
            int h = col >> 6, d = col & 63;
            size_t base = (size_t)(bx * NH + h) * DKH * SEQLEN + (size_t)d * SEQLEN
                        + (m0 & 2047) + rd_s;
            ushort8 x0 = *(ushort8*)&t_lds[rd_c * 136 + rd_s];
            ushort8 x1 = *(ushort8*)&t_lds[rd_c * 136 + rd_s + 8];
            *(ushort8*)&v_ws[base]     = x0;
            *(ushort8*)&v_ws[base + 8] = x1;
        }
    } else {
        // ---- Q/K: fused RoPE on fp32 acc, then round once ----
        unsigned short* dst = (z == 0) ? q_ws : k_ws;
        const float sc = (z == 0) ? QSCALE : 1.0f;
        #pragma unroll
        for (int mi = 0; mi < 4; mi++)
            #pragma unroll
            for (int ni = 0; ni < 4; ni++)
                #pragma unroll
                for (int r = 0; r < 4; r++) {
                    int row = m0 + wm * 64 + mi * 16 + quad * 4 + r;
                    int col = n0 + wn * 64 + ni * 16 + l16;
                    int b = row >> 11, s = row & 2047;
                    int h = col >> 6,  d = col & 63;
                    float val = acc[mi][ni][r];
                    float other = __shfl_xor(val, 1);     // RoPE partner: col^1 == lane^1
                    float2 cs = tbl[s * 32 + (d >> 1)];
                    float rv = (d & 1) ? (other * cs.y + val * cs.x)
                                       : (val * cs.x - other * cs.y);
                    dst[(size_t)(b * NH + h) * SEQLEN * DKH + (size_t)s * DKH + d] =
                        f2bf(rv * sc);
                }
    }
}

// ---------- kernel 2: causal flash attention (S^T trick; 128q x 128k blocks) ----------
// grid (bh=32, y=16): one q-supertile per block. qt = (y<8) ? y : 23-y, so blocks
// ID c and c+256 (same CU under round-robin dispatch) carry qt pairs (a, 15-a):
// every CU gets 17 key-tile iterations total with TWO resident blocks.
// launch_bounds (512, 2): (512,4) forced 64-VGPR cap -> scratch spills (+20us).
// ID%8 = bh%8 -> all blocks of one bh on one XCD (K/V L2 locality).
// waves 0-3 take keys [s0,s0+64), waves 4-7 keys [s0+64,s0+128); group-1 partials
// combined into group 0 through an LDS buffer aliased over k_lds/v_lds at the end.
// S^T = K·Q^T: C-layout lane holds P[q=l16][key=quad*4+r] == B-operand layout of
// mfma_16x16x16 -> PV without cross-lane transform. O^T in C-layout.
__global__ __launch_bounds__(512, 2)
void attn_kernel(const unsigned short* __restrict__ q_ws,
                 const unsigned short* __restrict__ k_ws,
                 const unsigned short* __restrict__ v_ws,
                 unsigned short* __restrict__ ao)
{
    // k_lds 128*72 ushorts (18432B) + v_lds 64*136 ushorts (17408B) = 35840B.
    // Reduction view (aliased): redO 8192 f32 (32KB) + redL 512 f32 (2KB) = 34816B.
    __shared__ __align__(16) unsigned short smem[17920];
    unsigned short* k_lds = smem;                 // [key][d] pad->72
    unsigned short* v_lds = smem + 128 * 72;      // [d][key] pad->136
    float* redO = (float*)smem;
    float* redL = redO + 8192;

    const int bh  = blockIdx.x;
    const int y   = blockIdx.y;         // 0..15
    const int qt2 = (y < 8) ? y : (23 - y);   // CU-pairing balance map
    const int tid = threadIdx.x, lane = tid & 63, w = tid >> 6;
    const int quad = lane >> 4, l16 = lane & 15;
    const int g   = w >> 2;             // key-half group (0: keys 0-63, 1: keys 64-127)
    const int w4  = w & 3;              // query strip owner within group
    const int nf0 = g * 4;

    const size_t kqbase = (size_t)bh * SEQLEN * DKH;
    const size_t vbase  = (size_t)bh * DKH * SEQLEN;
    const int b = bh >> 4, h = bh & 15;

    // staging (512 threads, 2 chunks each)
    const int krow = tid >> 3, kcol = (tid & 7) * 8;     // K: rows krow, krow+64
    const int vrow = tid >> 4, vcol = (tid & 15) * 8;    // V: rows vrow, vrow+32

    const int q0  = qt2 * 128;
    const int nt  = qt2 + 1;              // # of 128-key tiles
    const int qwbase = q0 + w4 * 32;      // this wave's 32 queries

    short8 aq[2][2];
    #pragma unroll
    for (int st = 0; st < 2; st++)
        #pragma unroll
        for (int kc = 0; kc < 2; kc++)
            aq[st][kc] = *(const short8*)(q_ws + kqbase +
                (size_t)(qwbase + st * 16 + l16) * DKH + kc * 32 + quad * 8);

    f32x4 o_acc[2][4];
    #pragma unroll
    for (int st = 0; st < 2; st++)
        #pragma unroll
        for (int df = 0; df < 4; df++) { f32x4 z = {0.f,0.f,0.f,0.f}; o_acc[st][df] = z; }
    float lsum[2] = {0.f, 0.f};

    // prefetch tile 0
    ushort8 kreg[2], vreg[2];
    #pragma unroll
    for (int rr = 0; rr < 2; ++rr) {
        kreg[rr] = *(const ushort8*)(k_ws + kqbase + (size_t)(krow + rr * 64) * DKH + kcol);
        vreg[rr] = *(const ushort8*)(v_ws + vbase + (size_t)(vrow + rr * 32) * SEQLEN + vcol);
    }

    for (int t = 0; t < nt; ++t) {
        const int s0 = t * 128;
        __syncthreads();
        #pragma unroll
        for (int rr = 0; rr < 2; ++rr) {
            *(ushort8*)&k_lds[(krow + rr * 64) * 72 + kcol]  = kreg[rr];
            *(ushort8*)&v_lds[(vrow + rr * 32) * 136 + vcol] = vreg[rr];
        }
        __syncthreads();
        if (t < nt - 1) {
            int s1 = s0 + 128;
            #pragma unroll
            for (int rr = 0; rr < 2; ++rr) {
                kreg[rr] = *(const ushort8*)(k_ws + kqbase + (size_t)(s1 + krow + rr * 64) * DKH + kcol);
                vreg[rr] = *(const ushort8*)(v_ws + vbase + (size_t)(vrow + rr * 32) * SEQLEN + s1 + vcol);
            }
        }

        const bool diag = (t == nt - 1);
        #pragma unroll
        for (int nfi = 0; nfi < 4; nfi++) {
            const int nf = nf0 + nfi;
            short8 kf0 = *(const short8*)&k_lds[(nf * 16 + l16) * 72 + 0 * 32 + quad * 8];
            short8 kf1 = *(const short8*)&k_lds[(nf * 16 + l16) * 72 + 1 * 32 + quad * 8];
            bf16x4 vf[4];
            #pragma unroll
            for (int df = 0; df < 4; df++)
                vf[df] = *(const bf16x4*)&v_lds[(df * 16 + l16) * 136 + nf * 16 + quad * 4];

            #pragma unroll
            for (int st = 0; st < 2; st++) {
                f32x4 s = {0.f,0.f,0.f,0.f};
                s = __builtin_amdgcn_mfma_f32_16x16x32_bf16(kf0, aq[st][0], s, 0, 0, 0);
                s = __builtin_amdgcn_mfma_f32_16x16x32_bf16(kf1, aq[st][1], s, 0, 0, 0);

                if (diag) {
                    int qg = qwbase + st * 16 + l16;
                    int kg = s0 + nf * 16 + quad * 4;
                    #pragma unroll
                    for (int r = 0; r < 4; r++)
                        s[r] = (kg + r <= qg) ? __builtin_amdgcn_exp2f(s[r]) : 0.f;
                } else {
                    #pragma unroll
                    for (int r = 0; r < 4; r++)
                        s[r] = __builtin_amdgcn_exp2f(s[r]);
                }
                lsum[st] += s[0] + s[1] + s[2] + s[3];

                union { unsigned u[2]; bf16x4 v; } pk;
                pk.u[0] = __builtin_amdgcn_perm(fbits(s[1]), fbits(s[0]), 0x07060302u);
                pk.u[1] = __builtin_amdgcn_perm(fbits(s[3]), fbits(s[2]), 0x07060302u);

                #pragma unroll
                for (int df = 0; df < 4; df++)
                    o_acc[st][df] = __builtin_amdgcn_mfma_f32_16x16x16bf16_1k(vf[df], pk.v, o_acc[st][df], 0, 0, 0);
            }
        }
    }

    // ---- combine group 1 partials into group 0 through LDS, then epilogue ----
    __syncthreads();                       // all waves done reading k_lds/v_lds
    if (g == 1) {
        #pragma unroll
        for (int st = 0; st < 2; st++) {
            #pragma unroll
            for (int df = 0; df < 4; df++)
                *(f32x4*)&redO[(((w4 * 2 + st) * 4 + df) << 8) + lane * 4] = o_acc[st][df];
            redL[(w4 * 2 + st) * 64 + lane] = lsum[st];
        }
    }
    __syncthreads();
    if (g == 0) {
        #pragma unroll
        for (int st = 0; st < 2; st++) {
            #pragma unroll
            for (int df = 0; df < 4; df++) {
                f32x4 o1 = *(const f32x4*)&redO[(((w4 * 2 + st) * 4 + df) << 8) + lane * 4];
                o_acc[st][df] += o1;
            }
            float rs = lsum[st] + redL[(w4 * 2 + st) * 64 + lane];
            rs += __shfl_xor(rs, 16);
            rs += __shfl_xor(rs, 32);
            float inv = 1.0f / rs;
            int qg = qwbase + st * 16 + l16;
            #pragma unroll
            for (int df = 0; df < 4; df++) {
                usht4 ov;
                #pragma unroll
                for (int r = 0; r < 4; r++) ov[r] = f2bf(o_acc[st][df][r] * inv);
                *(usht4*)&ao[(size_t)(b * SEQLEN + qg) * D_MODEL + h * DKH + df * 16 + quad * 4] = ov;
            }
        }
    }
}

// ---------- kernel 3: output projection (fp32 output), 128x64 tiles, dbuf ----------
__global__ __launch_bounds__(256, 2)
void gemm_out(const unsigned short* __restrict__ AO,
              const unsigned short* __restrict__ Wo,
              float* __restrict__ out)
{
    __shared__ __align__(16) unsigned short a_lds[2 * 128 * 64];   // 32 KB
    __shared__ __align__(16) unsigned short b_lds[2 * 64 * 64];    // 16 KB

    const int m0 = blockIdx.x * 128, n0 = blockIdx.y * 64;
    f32x4 acc[4][2];
    gemm_core_128x64_db(AO, Wo, a_lds, b_lds, m0, n0, acc);

    const int lane = threadIdx.x & 63;
    const int w    = threadIdx.x >> 6;
    const int quad = lane >> 4;
    const int l16  = lane & 15;
    const int wm   = w & 1, wn = w >> 1;

    #pragma unroll
    for (int mi = 0; mi < 4; mi++)
        #pragma unroll
        for (int ni = 0; ni < 2; ni++)
            #pragma unroll
            for (int r = 0; r < 4; r++) {
                int row = m0 + wm * 64 + mi * 16 + quad * 4 + r;
                int col = n0 + wn * 32 + ni * 16 + l16;
                out[(size_t)row * D_MODEL + col] = acc[mi][ni][r];
            }
}

// ---------- launch ----------
extern "C" void kernel_launch(void* const* d_in, const int* in_sizes, int n_in,
                              void* d_out, int out_size, void* d_ws, size_t ws_size,
                              hipStream_t stream) {
    const float* X  = (const float*)d_in[0];
    const int*   pos = (const int*)d_in[1];
    const float* Wq = (const float*)d_in[2];
    const float* Wk = (const float*)d_in[3];
    const float* Wv = (const float*)d_in[4];
    const float* Wo = (const float*)d_in[5];
    float* out = (float*)d_out;

    // ws (ushorts): Xb 4M | Wqb 1M | Wkb 1M | Wvb 1M | Wob 1M | q 4M | k 4M | v^T 4M | ao 4M | tbl 512KB
    unsigned short* Xb  = (unsigned short*)d_ws;
    unsigned short* Wqb = Xb + 4194304;
    unsigned short* Wkb = Wqb + 1048576;
    unsigned short* Wvb = Wkb + 1048576;
    unsigned short* Wob = Wvb + 1048576;
    unsigned short* q_ws = Wob + 1048576;
    unsigned short* k_ws = q_ws + 4194304;
    unsigned short* v_ws = k_ws + 4194304;
    unsigned short* ao   = v_ws + 4194304;
    float2* tbl = (float2*)(ao + 4194304);

    cvt_all<<<dim3(2048, 6), dim3(256), 0, stream>>>(X, Wq, Wk, Wv, Wo, pos,
                                                     Xb, Wqb, Wkb, Wvb, Wob, tbl);
    gemm_qkv<<<dim3(32, 8, 3), dim3(256), 0, stream>>>(Xb, Wqb, Wkb, Wvb, tbl, q_ws, k_ws, v_ws);
    attn_kernel<<<dim3(32, 16), dim3(512), 0, stream>>>(q_ws, k_ws, v_ws, ao);
    gemm_out<<<dim3(32, 16), dim3(256), 0, stream>>>(ao, Wob, out);
}